// Round 1
// baseline (25.549 us; speedup 1.0000x reference)
//
#include <hip/hip_runtime.h>

#define POLY_N   16777216
#define POLY_DIM 16

__global__ __launch_bounds__(256) void poly_horner_kernel(
        const float* __restrict__ x,
        const float* __restrict__ w,
        float* __restrict__ out) {
    // Coefficients: wave-uniform address -> compiler emits scalar loads, L1/L2 hit.
    float c[POLY_DIM];
#pragma unroll
    for (int i = 0; i < POLY_DIM; ++i) c[i] = w[i];

    const int n4     = POLY_N / 4;              // N divisible by 4
    const int stride = gridDim.x * blockDim.x;
    const float4* __restrict__ x4 = reinterpret_cast<const float4*>(x);
    float4* __restrict__       o4 = reinterpret_cast<float4*>(out);

    for (int i = blockIdx.x * blockDim.x + threadIdx.x; i < n4; i += stride) {
        float4 v = x4[i];
        float4 r;

        float a;
        a = c[POLY_DIM - 1];
#pragma unroll
        for (int j = POLY_DIM - 2; j >= 0; --j) a = fmaf(a, v.x, c[j]);
        r.x = a;

        a = c[POLY_DIM - 1];
#pragma unroll
        for (int j = POLY_DIM - 2; j >= 0; --j) a = fmaf(a, v.y, c[j]);
        r.y = a;

        a = c[POLY_DIM - 1];
#pragma unroll
        for (int j = POLY_DIM - 2; j >= 0; --j) a = fmaf(a, v.z, c[j]);
        r.z = a;

        a = c[POLY_DIM - 1];
#pragma unroll
        for (int j = POLY_DIM - 2; j >= 0; --j) a = fmaf(a, v.w, c[j]);
        r.w = a;

        o4[i] = r;
    }
}

extern "C" void kernel_launch(void* const* d_in, const int* in_sizes, int n_in,
                              void* d_out, int out_size, void* d_ws, size_t ws_size,
                              hipStream_t stream) {
    const float* x = (const float*)d_in[0];
    const float* w = (const float*)d_in[1];
    float* out     = (float*)d_out;

    const int block = 256;
    const int n4    = POLY_N / 4;
    int grid = (n4 + block - 1) / block;       // 16384 blocks worth of float4 work
    if (grid > 2048) grid = 2048;              // grid-stride the rest (G11)

    poly_horner_kernel<<<grid, block, 0, stream>>>(x, w, out);
}